// Round 3
// baseline (524.866 us; speedup 1.0000x reference)
//
#include <hip/hip_runtime.h>
#include <math.h>

#define NWAY 5
#define NSUP 25
#define NZV  125
#define DF   640
#define NQ   75
#define TPB  640   // two batches per block: waves 0-4 batch A, 5-9 batch B
#define CHW  128   // staging chunk width (columns)
#define GSTR 132   // GBUF row stride in floats (128 + 4 pad, 16B-aligned rows)

// =====================================================================
// Fast transform: tf(x) = sign(x) * (g(|x|+1e-5) - g(1e-5)),
//   g(t) = ln(1/t+1)^{-1.3} = exp2(-1.3*log2(log2(1/t+1)) + A),
//   A = -1.3*log2(ln2) = 0.68739628. 4 transcendentals vs reference's 8.
// =====================================================================
__device__ __forceinline__ float gfun(float t) {
  const float l2 = __log2f(__builtin_amdgcn_rcpf(t) + 1.0f);
  return __builtin_amdgcn_exp2f(fmaf(-1.3f, __log2f(l2), 0.68739628f));
}
__device__ __forceinline__ float simple_tf(float x, float Cg) {
  const float s = gfun(fabsf(x) + 1e-5f) - Cg;
  return (x >= 0.0f) ? s : -s;
}

// Fast fp64 reciprocal: v_rcp_f64 + 2 Newton steps -> full fp64 accuracy
// (validated: absmax identical to exact-divide build). Inputs strictly >0.
__device__ __forceinline__ double fdrcp(double d) {
  double r;
  asm("v_rcp_f64 %0, %1" : "=v"(r) : "v"(d));
  r = r * fma(-d, r, 2.0);
  r = r * fma(-d, r, 2.0);
  return r;
}

// Constant-lane fp64 broadcast via v_readlane (VALU, off the LDS pipe).
__device__ __forceinline__ double bcastd(double v, const int srclane) {
  const int lo = __builtin_amdgcn_readlane(__double2loint(v), srclane);
  const int hi = __builtin_amdgcn_readlane(__double2hiint(v), srclane);
  return __hiloint2double(hi, lo);
}

// =====================================================================
// Per-half flag barrier: monotone counter in LDS, 5 waves per half.
// All waves of a workgroup are gang-resident -> spin is deadlock-free.
// Producer side: wave-wide s_waitcnt lgkmcnt(0) drains this wave's LDS
// writes before the signal; consumer side: counter>=target implies all
// 5 waves signalled (and thus drained). Replaces __syncthreads so the
// two halves' barrier schedules DECOUPLE (stall overlap between the
// co-resident batches) and no vmcnt(0) full-drain is imposed.
// =====================================================================
__device__ __forceinline__ void hbar(unsigned* c, unsigned& tgt,
                                     const int lane) {
  tgt += 5;
  asm volatile("s_waitcnt lgkmcnt(0)" ::: "memory");
  if (lane == 0)
    __hip_atomic_fetch_add(c, 1u, __ATOMIC_RELAXED,
                           __HIP_MEMORY_SCOPE_WORKGROUP);
  while (__hip_atomic_load(c, __ATOMIC_RELAXED,
                           __HIP_MEMORY_SCOPE_WORKGROUP) < tgt)
    __builtin_amdgcn_s_sleep(1);
  asm volatile("" ::: "memory");
}

// In-place Gauss-Jordan of 25x25 SPD; columns live on lanes BASE..BASE+24.
template <int BASE, int J>
__device__ __forceinline__ void gjp(double (&a)[25], const int lane,
                                    const bool act) {
  const double djj = bcastd(a[J], BASE + J);
  const double pinv = fdrcp(djj);
  if (act) a[J] = ((lane == BASE + J) ? 1.0 : a[J]) * pinv;
#pragma unroll
  for (int r = 0; r < 25; ++r) {
    if (r != J) {
      const double f = bcastd(a[r], BASE + J);
      if (act) a[r] = ((lane == BASE + J) ? 0.0 : a[r]) - f * a[J];
    }
  }
}
template <int BASE, int J = 0>
__device__ __forceinline__ void gjall(double (&a)[25], const int lane,
                                      const bool act) {
  if constexpr (J < 25) {
    gjp<BASE, J>(a, lane, act);
    gjall<BASE, J + 1>(a, lane, act);
  }
}

// Factorize (per half): hv <- row `lane` of Hinv_w; this half's wave-0
// lanes 32-56 additionally get Winv = (sum_k Hinv_k)^-1 rows.
// W accumulation: write-first sequential waves (no zero pass, no atomics
// -- the R2 LDS fp64 atomic variant regressed ~30us).
__device__ __forceinline__ void factorize(const double* Msh, const double* dd,
                                          double* W, double (&hv)[25],
                                          const int tl, const int lane,
                                          const int w, unsigned* bc,
                                          unsigned& bt) {
  if (lane < 25) {
#pragma unroll
    for (int j = 0; j < 25; ++j)
      hv[j] = Msh[lane * 26 + j] + ((j == lane) ? dd[lane * 5 + w] : 0.0);
  }
  gjall<0>(hv, lane, true);
#pragma unroll
  for (int k = 0; k < 5; ++k) {
    if (w == k && lane < 25) {
      if (k == 0) {
#pragma unroll
        for (int j = 0; j < 25; ++j) W[lane * 26 + j] = hv[j];
      } else {
#pragma unroll
        for (int j = 0; j < 25; ++j) W[lane * 26 + j] += hv[j];
      }
    }
    hbar(bc, bt, lane);
  }
  if (w == 0) {
    if (lane >= 32 && lane < 57) {
#pragma unroll
      for (int r = 0; r < 25; ++r) hv[r] = W[(lane - 32) * 26 + r];
    }
    gjall<32>(hv, lane, lane >= 32 && lane < 57);
  }
  // wave 0's Winv is consumed only by wave 0 itself -> no barrier needed
}

// KKT solve (per half). ZRS: rs==0; ZR: rx=rz=ry==0; ACC: accumulate.
// di = 1/dd precomputed -> per-solve divides become multiplies.
template <bool ZRS, bool ZR, bool ACC>
__device__ __forceinline__ void kkt_solve(
    const double* Msh, const double* dd, const double* di, double* tt,
    double* c1, double* c2, double* vv, double* gg, double* dyw,
    const double* rx, const double* rs, const double* rz, const double* ry,
    double (&hv)[25], double* dx, double* ds, double* dz, double* dy,
    const int tl, const int lane, const int w, unsigned* bc, unsigned& bt) {
  if (tl < NZV) {
    double t = ZR ? 0.0 : rz[tl];
    if (!ZRS) t -= rs[tl] * di[tl];
    tt[tl] = t;
  }
  hbar(bc, bt, lane);
  if (tl < NZV) {
    const int i = tl / 5, k = tl - i * 5;
    double acc = ZR ? 0.0 : -rx[tl];
#pragma unroll
    for (int j = 0; j < 25; ++j) acc += Msh[i * 26 + j] * tt[j * 5 + k];
    c1[tl] = acc;
  } else if (tl >= 128 && tl < 153) {
    const int i = tl - 128;
    double acc = ZR ? 0.0 : -ry[i];
#pragma unroll
    for (int k = 0; k < 5; ++k) acc += tt[i * 5 + k];
    c2[i] = acc;
  }
  hbar(bc, bt, lane);
  if (lane < 25) {
    double acc = 0.0;
#pragma unroll
    for (int j = 0; j < 25; ++j) acc += hv[j] * c1[j * 5 + w];
    vv[lane * 5 + w] = acc;
  }
  hbar(bc, bt, lane);
  if (w == 0) {  // gg then dy in the SAME wave: LDS program order suffices
    if (lane < 25) {
      double acc = -c2[lane];
#pragma unroll
      for (int k = 0; k < 5; ++k) acc += vv[lane * 5 + k];
      gg[lane] = acc;
    }
    if (lane >= 32 && lane < 57) {
      double acc = 0.0;
#pragma unroll
      for (int r = 0; r < 25; ++r) acc += hv[r] * gg[r];
      dyw[lane - 32] = acc;
      if (ACC) dy[lane - 32] += acc; else dy[lane - 32] = acc;
    }
  }
  hbar(bc, bt, lane);
  if (lane < 25) {
    double acc = 0.0;
#pragma unroll
    for (int j = 0; j < 25; ++j) acc += hv[j] * dyw[j];
    const int v = lane * 5 + w;
    const double u = vv[v] - acc;
    const double dzv = dd[v] * u;
    const double dxv = u - tt[v];
    const double dsv = ((ZRS ? 0.0 : -rs[v]) - dzv) * di[v];
    if (ACC) { dz[v] += dzv; dx[v] += dxv; ds[v] += dsv; }
    else     { dz[v]  = dzv; dx[v]  = dxv; ds[v]  = dsv; }
  }
  hbar(bc, bt, lane);
}

// Per-half block reduction: first wave of the half reduces buf[0..n).
__device__ __forceinline__ double bred(const double* buf, int n, int ismin,
                                       double* SCh, const int w,
                                       const int lane, unsigned* bc,
                                       unsigned& bt) {
  hbar(bc, bt, lane);
  if (w == 0) {
    double acc = ismin ? 1e300 : 0.0;
    for (int m = lane; m < n; m += 64) {
      const double v = buf[m];
      acc = ismin ? fmin(acc, v) : (acc + v);
    }
#pragma unroll
    for (int off = 32; off > 0; off >>= 1) {
      const double o = __shfl_xor(acc, off);
      acc = ismin ? fmin(acc, o) : (acc + o);
    }
    if (lane == 0) SCh[15] = acc;
  }
  hbar(bc, bt, lane);
  return SCh[15];
}

// stage CHW columns of RAW transformed train rows into GBUF[25][GSTR].
__device__ __forceinline__ void stage_chunk(const float* __restrict__ tb,
                                            const int ch, const bool us,
                                            const float Cg, float* GBUF,
                                            const int tl) {
  for (int idx = tl; idx < NSUP * CHW; idx += 320) {
    const int r = idx >> 7, cc = idx & (CHW - 1);
    float v = tb[r * DF + ch * CHW + cc];
    if (us) v = simple_tf(v, Cg);
    GBUF[r * GSTR + cc] = v;
  }
}

// =====================================================================
// qp_kernel: TWO batches per 640-thread block (waves 0-4 / 5-9), grid
// B/2 -> 1 block/CU, 10 waves resident. ALL intra-half sync via hbar
// (per-half flag barrier) so the two batches' stalls overlap instead of
// lock-stepping through block-wide __syncthreads. Out-phase is a
// separate kernel (fusing it was measured-negative: pure serial tail).
// =====================================================================
__global__ void __launch_bounds__(TPB, 2) qp_kernel(
    const float* __restrict__ train, const int* __restrict__ usimple,
    float* __restrict__ xfg, const int B) {
  const int tid = threadIdx.x;
  const int half = tid >= 320 ? 1 : 0;
  const int tl = tid - 320 * half;
  const int lane = tid & 63;
  const int w = tl >> 6;
  const int bb = 2 * blockIdx.x + half;
  const bool live = bb < B;
  const bool us = (usimple[0] != 0);
  const float Cg = gfun(1e-5f);

  // Flat per-half LDS pool (offsets in doubles). 2*3494*8 = 55904 B.
  // GBUF (1650 d) overlays the QP vectors x..rsc (dead during staging
  // phases); W (850 d) has its own region (live only in factorize).
  __shared__ __align__(16) double POOL[2][3494];
  __shared__ unsigned bctr[2];
  double* ph = POOL[half];
  double* Msh = ph + 0;      // 650
  double* x   = ph + 650;    // 125
  double* sv  = ph + 775;    // 125
  double* zv  = ph + 900;    // 125
  double* rx  = ph + 1025;   // 125
  double* rz  = ph + 1150;   // 125
  double* dd  = ph + 1275;   // 125
  double* di  = ph + 1400;   // 125 (1/dd)
  double* tt  = ph + 1525;   // 125
  double* c1  = ph + 1650;   // 125
  double* vv  = ph + 1775;   // 125
  double* dxa = ph + 1900;   // 125
  double* dsa = ph + 2025;   // 125
  double* dza = ph + 2150;   // 125
  double* rsc = ph + 2275;   // 125
  double* yv  = ph + 2400;   // 25
  double* ry  = ph + 2425;   // 25
  double* c2  = ph + 2450;   // 25 (also dinvn scratch pre-QP)
  double* gg  = ph + 2475;   // 25
  double* dya = ph + 2500;   // 25
  double* dyw = ph + 2525;   // 25
  double* SC  = ph + 2550;   // 16
  float*  invn = (float*)(ph + 2566);  // 25 floats
  float*  bxs  = (float*)(ph + 2579);  // 125 floats
  double* W    = ph + 2644;            // 850 doubles (factorize only)
  float*  GBUF = (float*)(ph + 650);   // 25*132 floats = 1650 doubles
  double* dinvn = c2;

  double hv[25];
  unsigned* bc = &bctr[half];
  unsigned bt = 0;

  if (tid < 2) bctr[tid] = 0;
  __syncthreads();  // the ONLY block-wide barrier

  const float* tb = train + (size_t)(live ? bb : 0) * NSUP * DF;

  // ---- phase 2: chunked RAW Gram G = F F^T (fp64 accumulate) ----
  int i1, j1, i2v = 0, j2v = 0;
  {
    int rem = tl, i = 0;
    while (rem >= NSUP - i) { rem -= NSUP - i; ++i; }
    i1 = i; j1 = i + rem;
  }
  if (tl < 5) {
    int rem = 320 + tl, i = 0;
    while (rem >= NSUP - i) { rem -= NSUP - i; ++i; }
    i2v = i; j2v = i + rem;
  }
  double acc1 = 0.0, acc2 = 0.0;
  for (int ch = 0; ch < DF / CHW; ++ch) {
    stage_chunk(tb, ch, us, Cg, GBUF, tl);
    hbar(bc, bt, lane);
    {
      const float4* ra = (const float4*)(GBUF + i1 * GSTR);
      const float4* rb = (const float4*)(GBUF + j1 * GSTR);
#pragma unroll
      for (int c = 0; c < CHW / 4; ++c) {
        float4 av = ra[c], bv = rb[c];
        acc1 += (double)av.x * bv.x + (double)av.y * bv.y +
                (double)av.z * bv.z + (double)av.w * bv.w;
      }
    }
    if (tl < 5) {
      const float4* ra = (const float4*)(GBUF + i2v * GSTR);
      const float4* rb = (const float4*)(GBUF + j2v * GSTR);
#pragma unroll
      for (int c = 0; c < CHW / 4; ++c) {
        float4 av = ra[c], bv = rb[c];
        acc2 += (double)av.x * bv.x + (double)av.y * bv.y +
                (double)av.z * bv.z + (double)av.w * bv.w;
      }
    }
    hbar(bc, bt, lane);
  }
  Msh[i1 * 26 + j1] = acc1;
  if (i1 != j1) Msh[j1 * 26 + i1] = acc1;
  if (tl < 5) {
    Msh[i2v * 26 + j2v] = acc2;
    if (i2v != j2v) Msh[j2v * 26 + i2v] = acc2;
  }
  hbar(bc, bt, lane);

  // ---- norms from Gram diagonal; then scale M = D G D + I ----
  if (tl < 25) {
    const double g = Msh[tl * 27];
    const double dn = 1.0 / fmax(sqrt(g), 1e-12);
    dinvn[tl] = dn;
    invn[tl] = (float)dn;
  }
  hbar(bc, bt, lane);
  for (int idx = tl; idx < 650; idx += 320) {
    const int i = idx / 26, j = idx - i * 26;
    if (j < 25) {
      double v = Msh[idx] * dinvn[i] * dinvn[j];
      if (i == j) v += 1.0;
      Msh[idx] = v;
    }
  }

  // ---- phase 3: QP init ----
  if (tl < NZV) {
    const int i = tl / 5, k = tl - i * 5;
    const double oh = (k == (i % 5)) ? 1.0 : 0.0;
    rx[tl] = -oh;
    rz[tl] = -0.1 * oh;
    dd[tl] = 1.0;
    di[tl] = 1.0;
  } else if (tl >= 128 && tl < 153) {
    ry[tl - 128] = 0.0;
  }
  if (tl == 0) SC[0] = 1e300;
  hbar(bc, bt, lane);

  factorize(Msh, dd, W, hv, tl, lane, w, bc, bt);
  kkt_solve<true, false, false>(Msh, dd, di, tt, c1, c2, vv, gg, dyw, rx,
                                (const double*)nullptr, rz, ry, hv, x, sv, zv,
                                yv, tl, lane, w, bc, bt);
  {
    const double ms = bred(sv, NZV, 1, SC, w, lane, bc, bt);
    if (ms < 0.0 && tl < NZV) sv[tl] -= (ms - 1.0);
    const double mz = bred(zv, NZV, 1, SC, w, lane, bc, bt);
    if (mz < 0.0 && tl < NZV) zv[tl] -= (mz - 1.0);
  }
  if (tl < NZV) bxs[tl] = (float)x[tl];

#pragma unroll 1
  for (int it = 0; it < 3; ++it) {
    hbar(bc, bt, lane);
    if (tl < NZV) {
      const int i = tl / 5, k = tl - i * 5;
      double acc = 0.0;
#pragma unroll
      for (int j = 0; j < 25; ++j) acc += Msh[i * 26 + j] * x[j * 5 + k];
      const double oh = (k == (i % 5)) ? 1.0 : 0.0;
      rx[tl] = yv[i] + zv[tl] + acc - oh;
      rz[tl] = x[tl] + sv[tl] - 0.1 * oh;
    } else if (tl >= 128 && tl < 153) {
      const int i = tl - 128;
      double acc = 0.0;
#pragma unroll
      for (int k = 0; k < 5; ++k) acc += x[i * 5 + k];
      ry[i] = acc;
    }
    hbar(bc, bt, lane);
    if (w == 0) {  // per-half consolidated 4-sum reduction (first wave)
      double s1 = 0, s2 = 0, s3 = 0, s4 = 0;
      for (int m = lane; m < 125; m += 64) {
        s1 += sv[m] * zv[m];
        s2 += rx[m] * rx[m];
        s3 += rz[m] * rz[m];
      }
      if (lane < 25) s4 = ry[lane] * ry[lane];
#pragma unroll
      for (int off = 32; off > 0; off >>= 1) {
        s1 += __shfl_xor(s1, off);
        s2 += __shfl_xor(s2, off);
        s3 += __shfl_xor(s3, off);
        s4 += __shfl_xor(s4, off);
      }
      if (lane == 0) { SC[2] = s1; SC[3] = s2; SC[4] = s3; SC[5] = s4; }
    }
    hbar(bc, bt, lane);
    const double szsum = SC[2];
    const double mu = fabs(szsum) / 125.0;
    const double res = sqrt(SC[4] + 1e-30) + sqrt(SC[5] + 1e-30) +
                       sqrt(SC[3] + 1e-30) + 125.0 * mu;
    if (tl == 0) {
      if (res < SC[0]) { SC[0] = res; SC[1] = 1.0; } else SC[1] = 0.0;
    }
    hbar(bc, bt, lane);
    if (SC[1] != 0.0 && tl < NZV) bxs[tl] = (float)x[tl];
    if (it == 2) break;
    hbar(bc, bt, lane);

    if (tl < NZV) {
      dd[tl] = zv[tl] * fdrcp(sv[tl]);
      di[tl] = sv[tl] * fdrcp(zv[tl]);
    }
    hbar(bc, bt, lane);
    factorize(Msh, dd, W, hv, tl, lane, w, bc, bt);
    kkt_solve<false, false, false>(Msh, dd, di, tt, c1, c2, vv, gg, dyw, rx,
                                   zv, rz, ry, hv, dxa, dsa, dza, dya, tl,
                                   lane, w, bc, bt);
    if (tl < NZV) {
      const double a1 = (dza[tl] < 0.0) ? (-zv[tl] / dza[tl]) : 1e12;
      const double a2 = (dsa[tl] < 0.0) ? (-sv[tl] / dsa[tl]) : 1e12;
      tt[tl] = fmin(a1, a2);
    }
    const double aff = fmin(bred(tt, NZV, 1, SC, w, lane, bc, bt), 1.0);
    if (tl < NZV)
      tt[tl] = (sv[tl] + aff * dsa[tl]) * (zv[tl] + aff * dza[tl]);
    const double num = bred(tt, NZV, 0, SC, w, lane, bc, bt);
    const double sg = num / szsum;
    const double musig = mu * (sg * sg * sg);
    if (tl < NZV) rsc[tl] = (-musig + dsa[tl] * dza[tl]) * fdrcp(sv[tl]);
    hbar(bc, bt, lane);
    kkt_solve<false, true, true>(Msh, dd, di, tt, c1, c2, vv, gg, dyw, rx,
                                 rsc, rz, ry, hv, dxa, dsa, dza, dya, tl,
                                 lane, w, bc, bt);
    if (tl < NZV) {
      const double a1 = (dza[tl] < 0.0) ? (-zv[tl] / dza[tl]) : 1e12;
      const double a2 = (dsa[tl] < 0.0) ? (-sv[tl] / dsa[tl]) : 1e12;
      tt[tl] = fmin(a1, a2);
    }
    const double al = fmin(0.999 * bred(tt, NZV, 1, SC, w, lane, bc, bt),
                           1.0);
    if (tl < NZV) {
      x[tl] += al * dxa[tl];
      sv[tl] += al * dsa[tl];
      zv[tl] += al * dza[tl];
    } else if (tl >= 128 && tl < 153) {
      const int i = tl - 128;
      yv[i] += al * dya[i];
    }
  }
  hbar(bc, bt, lane);

  // ---- phase 4: xfg[w][d] = sum_s (bx[s,w]*invn[s]) * Fraw[s][d] ----
  float xs[25];
#pragma unroll
  for (int s_ = 0; s_ < 25; ++s_) xs[s_] = bxs[s_ * 5 + w] * invn[s_];
  for (int ch = 0; ch < DF / CHW; ++ch) {
    stage_chunk(tb, ch, us, Cg, GBUF, tl);
    hbar(bc, bt, lane);
    float accA = 0.0f, accB = 0.0f;
#pragma unroll
    for (int s_ = 0; s_ < 25; ++s_) {
      accA += xs[s_] * GBUF[s_ * GSTR + lane];
      accB += xs[s_] * GBUF[s_ * GSTR + 64 + lane];
    }
    if (live) {
      float* op = xfg + ((size_t)bb * NWAY + w) * DF + ch * CHW;
      op[lane] = accA;
      op[64 + lane] = accB;
    }
    hbar(bc, bt, lane);
  }
}

// =====================================================================
// Output kernel: one block per batch, 640 threads = 10 waves; wave u
// handles queries u, u+10, ... float4 loads (3/query vs 10 dword).
// =====================================================================
__global__ void __launch_bounds__(640) out_kernel(
    const float* __restrict__ test, const int* __restrict__ usimple,
    const float* __restrict__ xfg, float* __restrict__ out) {
  const int b = blockIdx.x;
  const int tid = threadIdx.x;
  const int lane = tid & 63;
  const int u = tid >> 6;   // 0..9
  const bool us = (usimple[0] != 0);
  const float Cg = gfun(1e-5f);

  __shared__ float xfs[NWAY * DF];
  for (int i = tid; i < NWAY * DF; i += 640)
    xfs[i] = xfg[(size_t)b * NWAY * DF + i];
  __syncthreads();
  const float4* xf4 = (const float4*)xfs;

  const float* qb = test + (size_t)b * NQ * DF;
#pragma unroll 2
  for (int jj = 0; jj < 8; ++jj) {
    const int q = u + 10 * jj;
    if (q >= NQ) break;
    const float4* qr4 = (const float4*)(qb + (size_t)q * DF);
    float nrm = 0.0f, a0 = 0.0f, a1 = 0.0f, a2 = 0.0f, a3 = 0.0f, a4 = 0.0f;
#pragma unroll
    for (int c = 0; c < 3; ++c) {
      if (c < 2 || lane < 32) {
        const int f4i = lane + 64 * c;
        float4 v = qr4[f4i];
        if (us) {
          v.x = simple_tf(v.x, Cg);
          v.y = simple_tf(v.y, Cg);
          v.z = simple_tf(v.z, Cg);
          v.w = simple_tf(v.w, Cg);
        }
        nrm += v.x * v.x + v.y * v.y + v.z * v.z + v.w * v.w;
        float4 t;
        t = xf4[0 * (DF / 4) + f4i];
        a0 += v.x * t.x + v.y * t.y + v.z * t.z + v.w * t.w;
        t = xf4[1 * (DF / 4) + f4i];
        a1 += v.x * t.x + v.y * t.y + v.z * t.z + v.w * t.w;
        t = xf4[2 * (DF / 4) + f4i];
        a2 += v.x * t.x + v.y * t.y + v.z * t.z + v.w * t.w;
        t = xf4[3 * (DF / 4) + f4i];
        a3 += v.x * t.x + v.y * t.y + v.z * t.z + v.w * t.w;
        t = xf4[4 * (DF / 4) + f4i];
        a4 += v.x * t.x + v.y * t.y + v.z * t.z + v.w * t.w;
      }
    }
#pragma unroll
    for (int off = 32; off > 0; off >>= 1) {
      nrm += __shfl_xor(nrm, off);
      a0 += __shfl_xor(a0, off);
      a1 += __shfl_xor(a1, off);
      a2 += __shfl_xor(a2, off);
      a3 += __shfl_xor(a3, off);
      a4 += __shfl_xor(a4, off);
    }
    if (lane == 0) {
      const float sc = 1.0f / fmaxf(sqrtf(nrm), 1e-12f);
      float* op = out + ((size_t)b * NQ + q) * 5;
      op[0] = a0 * sc;
      op[1] = a1 * sc;
      op[2] = a2 * sc;
      op[3] = a3 * sc;
      op[4] = a4 * sc;
    }
  }
}

// =====================================================================
extern "C" void kernel_launch(void* const* d_in, const int* in_sizes, int n_in,
                              void* d_out, int out_size, void* d_ws,
                              size_t ws_size, hipStream_t stream) {
  const float* ftest = (const float*)d_in[0];
  const float* ftrain = (const float*)d_in[1];
  const int* usimple = (const int*)d_in[4];
  float* out = (float*)d_out;
  const int B = in_sizes[1] / (NSUP * DF);

  float* xfg = (float*)d_ws;  // B * 5 * 640 floats

  qp_kernel<<<dim3((B + 1) / 2), dim3(TPB), 0, stream>>>(ftrain, usimple,
                                                         xfg, B);
  out_kernel<<<dim3(B), dim3(640), 0, stream>>>(ftest, usimple, xfg, out);
}